// Round 2
// baseline (85.937 us; speedup 1.0000x reference)
//
#include <hip/hip_runtime.h>

#define EPS 1e-8f

constexpr int NROWS = 1024;
constexpr int K     = 256;
constexpr int TM    = 128;   // output tile rows per block
constexpr int TN    = 128;   // output tile cols per block
constexpr int KC    = 64;    // k-slice per block (split-K)
constexpr int KZ    = 4;     // number of k slices

// d_ws layout:
//   [0, 8 KB):            sums[2048] (Sx then Sy)
//   [64 KB, 64 KB+16 MB): partials[KZ][1024][1024] f32
constexpr size_t PART_OFF = 65536;

// ---------------- Kernel A: row sums ----------------
__global__ __launch_bounds__(256) void rowsum_kernel(const float* __restrict__ x,
                                                     const float* __restrict__ y,
                                                     float* __restrict__ sums) {
    const int wave = threadIdx.x >> 6;
    const int lane = threadIdx.x & 63;
    const int row  = blockIdx.x * 4 + wave;   // 0..2047
    const float* src = (row < NROWS) ? (x + (size_t)row * K)
                                     : (y + (size_t)(row - NROWS) * K);
    float4 v = ((const float4*)src)[lane];
    float s = v.x + v.y + v.z + v.w;
    #pragma unroll
    for (int off = 32; off > 0; off >>= 1) s += __shfl_down(s, off);
    if (lane == 0) sums[row] = s;
}

// ---------------- Kernel B: split-K partial min-sums ----------------
// Grid (8, 8, 4). 128x128 tile, 8x8 microtile/thread, one KC=64 slice.
// LDS: 256 rows x 64 floats, XOR-swizzled: float4 col c4 stored at c4^(row&7).
//  - a-reads: rows ty+16r, swz=ty&7 -> 4 distinct bank groups per wave (bcast x16)
//  - b-reads: rows 128+tx+16c, swz=tx&7 -> 2-way alias only (free)
__global__ __launch_bounds__(256) void partial_kernel(const float* __restrict__ x,
                                                      const float* __restrict__ y,
                                                      float* __restrict__ part) {
    __shared__ float lds[256 * 64];   // 64 KB

    const int tid = threadIdx.x;
    const int rowBase = blockIdx.y * TM;
    const int colBase = blockIdx.x * TN;
    const int kbase   = blockIdx.z * KC;

    // ---- stage x rows (LDS rows 0..127) and y rows (128..255) ----
    {
        const int col4 = tid & 15;     // float4 index within 64-float row
        const int r0   = tid >> 4;     // 0..15
        #pragma unroll
        for (int i = 0; i < 16; ++i) {
            const int row_s = r0 + 16 * i;   // 0..255
            const float* src = (row_s < 128)
                ? &x[(size_t)(rowBase + row_s) * K + kbase + col4 * 4]
                : &y[(size_t)(colBase + row_s - 128) * K + kbase + col4 * 4];
            const float4 v = *(const float4*)src;
            const int c4 = col4 ^ (row_s & 7);
            *(float4*)&lds[row_s * 64 + c4 * 4] = v;
        }
    }
    __syncthreads();

    const int ty = tid >> 4;   // 0..15 -> rows ty+16r
    const int tx = tid & 15;   // 0..15 -> cols tx+16c
    const int aswz = ty & 7;
    const int bswz = tx & 7;

    float acc[8][8];
    #pragma unroll
    for (int r = 0; r < 8; ++r)
        #pragma unroll
        for (int c = 0; c < 8; ++c) acc[r][c] = 0.0f;

    #pragma unroll
    for (int kk4 = 0; kk4 < 16; ++kk4) {
        float4 a[8], b[8];
        const int ac = (kk4 ^ aswz) * 4;
        const int bc = (kk4 ^ bswz) * 4;
        #pragma unroll
        for (int r = 0; r < 8; ++r) a[r] = *(const float4*)&lds[(ty + 16 * r) * 64 + ac];
        #pragma unroll
        for (int c = 0; c < 8; ++c) b[c] = *(const float4*)&lds[(128 + tx + 16 * c) * 64 + bc];
        #pragma unroll
        for (int r = 0; r < 8; ++r)
            #pragma unroll
            for (int c = 0; c < 8; ++c) {
                const float m0 = fminf(a[r].x, b[c].x);
                const float m1 = fminf(a[r].y, b[c].y);
                const float m2 = fminf(a[r].z, b[c].z);
                const float m3 = fminf(a[r].w, b[c].w);
                acc[r][c] += (m0 + m1) + (m2 + m3);
            }
    }

    // ---- store partial tile (4 rows x 16 consecutive cols per wave-inst) ----
    float* p = part + (size_t)blockIdx.z * NROWS * NROWS;
    #pragma unroll
    for (int r = 0; r < 8; ++r) {
        const size_t rowOff = (size_t)(rowBase + ty + 16 * r) * NROWS + colBase;
        #pragma unroll
        for (int c = 0; c < 8; ++c)
            p[rowOff + tx + 16 * c] = acc[r][c];
    }
}

// ---------------- Kernel C: combine partials + epilogue ----------------
__global__ __launch_bounds__(256) void combine_kernel(const float* __restrict__ part,
                                                      const float* __restrict__ sums,
                                                      float* __restrict__ out) {
    const int idx4 = blockIdx.x * 256 + threadIdx.x;  // float4 index, 0..262143
    const int row  = idx4 >> 8;                       // 256 float4 per row
    const int col4 = idx4 & 255;

    const float4* p0 = (const float4*)part;
    const float4 v0 = p0[idx4];
    const float4 v1 = p0[idx4 + (NROWS * NROWS / 4)];
    const float4 v2 = p0[idx4 + 2 * (NROWS * NROWS / 4)];
    const float4 v3 = p0[idx4 + 3 * (NROWS * NROWS / 4)];

    float4 n;
    n.x = (v0.x + v1.x) + (v2.x + v3.x);
    n.y = (v0.y + v1.y) + (v2.y + v3.y);
    n.z = (v0.z + v1.z) + (v2.z + v3.z);
    n.w = (v0.w + v1.w) + (v2.w + v3.w);

    const float  sx = sums[row];
    const float4 sy = *(const float4*)&sums[NROWS + col4 * 4];

    float4 o;
    o.x = n.x / (sx + sy.x - n.x + EPS);
    o.y = n.y / (sx + sy.y - n.y + EPS);
    o.z = n.z / (sx + sy.z - n.z + EPS);
    o.w = n.w / (sx + sy.w - n.w + EPS);
    ((float4*)out)[idx4] = o;
}

extern "C" void kernel_launch(void* const* d_in, const int* in_sizes, int n_in,
                              void* d_out, int out_size, void* d_ws, size_t ws_size,
                              hipStream_t stream) {
    const float* x = (const float*)d_in[0];
    const float* y = (const float*)d_in[1];
    float* out   = (float*)d_out;
    float* sums  = (float*)d_ws;
    float* parts = (float*)((char*)d_ws + PART_OFF);

    rowsum_kernel<<<dim3(2048 / 4), dim3(256), 0, stream>>>(x, y, sums);
    partial_kernel<<<dim3(NROWS / TN, NROWS / TM, KZ), dim3(256), 0, stream>>>(x, y, parts);
    combine_kernel<<<dim3(NROWS * NROWS / 4 / 256), dim3(256), 0, stream>>>(parts, sums, out);
}